// Round 1
// baseline (299.858 us; speedup 1.0000x reference)
//
#include <hip/hip_runtime.h>
#include <hip/hip_bf16.h>
#include <cstdint>

// Problem constants (match reference)
#define B_SZ     256
#define D_DIM    2048
#define N_PROXY  16384
#define P_POS    4
#define K_SEL    54        // BG_KNN + P
#define TEMP_INV 20.0f     // 1/0.05

typedef __bf16 bf16_t;
typedef __bf16 bf16x4 __attribute__((ext_vector_type(4)));
typedef __bf16 bf16x8 __attribute__((ext_vector_type(8)));
typedef float  f32x4  __attribute__((ext_vector_type(4)));

// ---------------------------------------------------------------------------
// Kernel 1: score = (features @ em.T) * (1/TEMP), fp32 in, bf16 MFMA compute.
// Tile: BM=128, BN=128, BK=32; 256 threads = 4 waves in 2x2, wave tile 64x64.
// Grid: (N/128=128, M/128=2).
// ---------------------------------------------------------------------------
__global__ __launch_bounds__(256)
void gemm_score(const float* __restrict__ F, const float* __restrict__ E,
                float* __restrict__ S) {
    const int tid  = threadIdx.x;
    const int bn   = blockIdx.x;     // N tile
    const int bm   = blockIdx.y;     // M tile
    const int lane = tid & 63;
    const int wave = tid >> 6;
    const int wm   = wave >> 1;      // 0..1
    const int wn   = wave & 1;       // 0..1

    // padded stride 40 bf16 (=80B): rows 2-way bank alias only (free), 16B aligned
    __shared__ bf16_t As[128 * 40];
    __shared__ bf16_t Bs[128 * 40];

    f32x4 acc[4][4] = {};

    const float* Fbase = F + (size_t)(bm * 128) * D_DIM;
    const float* Ebase = E + (size_t)(bn * 128) * D_DIM;

    const int frow = lane & 15;   // fragment row within 16
    const int quad = lane >> 4;   // 0..3 -> k offset quad*8

    for (int k0 = 0; k0 < D_DIM; k0 += 32) {
        // ---- stage 128x32 fp32 -> bf16 LDS, both tiles, fully coalesced ----
#pragma unroll
        for (int j = 0; j < 4; ++j) {
            int l   = j * 256 + tid;       // 0..1023 float4 slots (128 rows x 8)
            int row = l >> 3;
            int c   = l & 7;               // float4 index within 32-wide row
            float4 va = *(const float4*)(Fbase + (size_t)row * D_DIM + k0 + c * 4);
            float4 vb = *(const float4*)(Ebase + (size_t)row * D_DIM + k0 + c * 4);
            bf16x4 ha = { (bf16_t)va.x, (bf16_t)va.y, (bf16_t)va.z, (bf16_t)va.w };
            bf16x4 hb = { (bf16_t)vb.x, (bf16_t)vb.y, (bf16_t)vb.z, (bf16_t)vb.w };
            *(bf16x4*)(As + row * 40 + c * 4) = ha;
            *(bf16x4*)(Bs + row * 40 + c * 4) = hb;
        }
        __syncthreads();

        // ---- fragments: A[m=lane&15][k=quad*8+j], same packing for B rows ----
        bf16x8 af[4], bfr[4];
#pragma unroll
        for (int m = 0; m < 4; ++m)
            af[m] = *(const bf16x8*)(As + (wm * 64 + m * 16 + frow) * 40 + quad * 8);
#pragma unroll
        for (int n = 0; n < 4; ++n)
            bfr[n] = *(const bf16x8*)(Bs + (wn * 64 + n * 16 + frow) * 40 + quad * 8);

#pragma unroll
        for (int m = 0; m < 4; ++m)
#pragma unroll
            for (int n = 0; n < 4; ++n)
                acc[m][n] = __builtin_amdgcn_mfma_f32_16x16x32_bf16(
                    af[m], bfr[n], acc[m][n], 0, 0, 0);
        __syncthreads();
    }

    // ---- epilogue: C/D layout col=lane&15, row=quad*4+i; fold 1/TEMP ----
    const int ccol = lane & 15;
#pragma unroll
    for (int m = 0; m < 4; ++m) {
        int gr = bm * 128 + wm * 64 + m * 16 + quad * 4;
#pragma unroll
        for (int n = 0; n < 4; ++n) {
            int gc = bn * 128 + wn * 64 + n * 16 + ccol;
#pragma unroll
            for (int i = 0; i < 4; ++i)
                S[(size_t)(gr + i) * N_PROXY + gc] = acc[m][n][i] * TEMP_INV;
        }
    }
}

// ---------------------------------------------------------------------------
// Kernel 2: per-row top-K + log-softmax loss. One block (256 thr) per row.
// 64 logits/thread held as order-preserving uint keys in registers.
// ---------------------------------------------------------------------------
__device__ __forceinline__ float key_to_float(uint32_t k) {
    uint32_t bits = (k & 0x80000000u) ? (k ^ 0x80000000u) : ~k;
    return __uint_as_float(bits);
}

__device__ __forceinline__ int block_sum_i(int v, int tid, volatile int* rbuf) {
#pragma unroll
    for (int o = 32; o > 0; o >>= 1) v += __shfl_down(v, o, 64);
    __syncthreads();                       // protect rbuf from previous use
    if ((tid & 63) == 0) rbuf[tid >> 6] = v;
    __syncthreads();
    return rbuf[0] + rbuf[1] + rbuf[2] + rbuf[3];
}

__device__ __forceinline__ float block_sum_f(float v, int tid, volatile float* rbuf) {
#pragma unroll
    for (int o = 32; o > 0; o >>= 1) v += __shfl_down(v, o, 64);
    __syncthreads();
    if ((tid & 63) == 0) rbuf[tid >> 6] = v;
    __syncthreads();
    return rbuf[0] + rbuf[1] + rbuf[2] + rbuf[3];
}

__device__ __forceinline__ uint32_t block_max_u(uint32_t v, int tid, volatile uint32_t* rbuf) {
#pragma unroll
    for (int o = 32; o > 0; o >>= 1) {
        uint32_t w = __shfl_down(v, o, 64);
        v = (w > v) ? w : v;
    }
    __syncthreads();
    if ((tid & 63) == 0) rbuf[tid >> 6] = v;
    __syncthreads();
    uint32_t r = rbuf[0];
    r = rbuf[1] > r ? rbuf[1] : r;
    r = rbuf[2] > r ? rbuf[2] : r;
    r = rbuf[3] > r ? rbuf[3] : r;
    return r;
}

// largest T with count(keys >= T) >= k  == k-th largest key (k >= 1)
__device__ __forceinline__ uint32_t radix_kth(const uint32_t (&keys)[64], int k,
                                              int tid, volatile int* rbuf) {
    uint32_t T = 0;
    for (int bit = 31; bit >= 0; --bit) {
        uint32_t cand = T | (1u << bit);
        int c = 0;
#pragma unroll
        for (int j = 0; j < 64; ++j) c += (keys[j] >= cand) ? 1 : 0;
        if (block_sum_i(c, tid, rbuf) >= k) T = cand;
    }
    return T;
}

__global__ __launch_bounds__(256)
void topk_loss(const float* __restrict__ S, const int* __restrict__ targets,
               const int* __restrict__ plabel, const int* __restrict__ ptable,
               float* __restrict__ out) {
    const int b   = blockIdx.x;
    const int tid = threadIdx.x;

    __shared__ int   sh_pos[4];
    __shared__ float sh_pv[4];
    __shared__ int   sh_d;
    __shared__ int      rbuf_i[4];
    __shared__ float    rbuf_f[4];
    __shared__ uint32_t rbuf_u[4];

    const float* row = S + (size_t)b * N_PROXY;

    if (tid == 0) {
        int t  = targets[b];
        int py = plabel[t];
        int pos[4]; int d = 0;
        for (int j = 0; j < 4; ++j) {
            int p = ptable[py * 4 + j];
            bool dup = false;
            for (int i = 0; i < d; ++i) dup = dup || (pos[i] == p);
            if (!dup) pos[d++] = p;
        }
        sh_d = d;
        for (int j = 0; j < 4; ++j) sh_pos[j] = (j < d) ? pos[j] : -1;
        for (int j = 0; j < 4; ++j) sh_pv[j]  = (j < d) ? row[pos[j]] : 0.0f;
    }
    __syncthreads();

    const int d  = sh_d;
    const int p0 = sh_pos[0], p1 = sh_pos[1], p2 = sh_pos[2], p3 = sh_pos[3];
    float pv[4];
#pragma unroll
    for (int j = 0; j < 4; ++j) pv[j] = sh_pv[j];

    // ---- load 64 logits/thread as sortable keys; positives excluded (key=0) ----
    uint32_t keys[64];
#pragma unroll
    for (int j = 0; j < 16; ++j) {
        int f4 = j * 256 + tid;
        float4 v = *(const float4*)(row + (size_t)f4 * 4);
        float vv[4] = { v.x, v.y, v.z, v.w };
#pragma unroll
        for (int q = 0; q < 4; ++q) {
            int idx = f4 * 4 + q;
            bool isp = (idx == p0) | (idx == p1) | (idx == p2) | (idx == p3);
            uint32_t bits = __float_as_uint(vv[q]);
            uint32_t key  = (bits & 0x80000000u) ? ~bits : (bits | 0x80000000u);
            keys[j * 4 + q] = isp ? 0u : key;
        }
    }

    const int need = K_SEL - d;                         // 50..53 backgrounds
    uint32_t T1 = radix_kth(keys, need, tid, rbuf_i);   // need-th largest bg key
    const float vT1 = key_to_float(T1);

    // max background key -> stability max; include positives
    uint32_t kmax = 0;
#pragma unroll
    for (int j = 0; j < 64; ++j) kmax = keys[j] > kmax ? keys[j] : kmax;
    kmax = block_max_u(kmax, tid, rbuf_u);
    float mx = key_to_float(kmax);
    for (int j = 0; j < 4; ++j) if (j < d && pv[j] > mx) mx = pv[j];

    // strict-greater stats + sumexp over strict-greater
    int c1 = 0; float se = 0.0f;
#pragma unroll
    for (int j = 0; j < 64; ++j) {
        if (keys[j] > T1) { c1 += 1; se += __expf(key_to_float(keys[j]) - mx); }
    }
    int   c1t = block_sum_i(c1, tid, rbuf_i);
    float set = block_sum_f(se, tid, rbuf_f);
    set += (float)(need - c1t) * __expf(vT1 - mx);
    for (int j = 0; j < 4; ++j) if (j < d) set += __expf(pv[j] - mx);
    const float lse = mx + logf(set);

    // numerator: distinct positives + top (P-d) background values
    float num = 0.0f;
    for (int j = 0; j < 4; ++j) if (j < d) num += pv[j];
    if (d < P_POS) {
        const int need2 = P_POS - d;                    // 1..3
        uint32_t T2 = radix_kth(keys, need2, tid, rbuf_i);
        int c2 = 0; float s2 = 0.0f;
#pragma unroll
        for (int j = 0; j < 64; ++j) {
            if (keys[j] > T2) { c2 += 1; s2 += key_to_float(keys[j]); }
        }
        int   c2t = block_sum_i(c2, tid, rbuf_i);
        float s2t = block_sum_f(s2, tid, rbuf_f);
        num += s2t + (float)(need2 - c2t) * key_to_float(T2);
    }

    const float loss_b = lse - num * (1.0f / P_POS);
    if (tid == 0) atomicAdd(out, loss_b * (1.0f / B_SZ));
}

// ---------------------------------------------------------------------------
extern "C" void kernel_launch(void* const* d_in, const int* in_sizes, int n_in,
                              void* d_out, int out_size, void* d_ws, size_t ws_size,
                              hipStream_t stream) {
    const float* F       = (const float*)d_in[0];   // features [256,2048]
    const float* E       = (const float*)d_in[1];   // global_memory [16384,2048]
    const int*   targets = (const int*)d_in[2];     // [256]
    const int*   plabel  = (const int*)d_in[3];     // [32768]
    const int*   ptable  = (const int*)d_in[4];     // [4096,4]
    float* S   = (float*)d_ws;                      // 256*16384 fp32 = 16 MB
    float* out = (float*)d_out;

    hipMemsetAsync(d_out, 0, sizeof(float), stream);

    dim3 ggrid(N_PROXY / 128, B_SZ / 128);          // (128, 2)
    hipLaunchKernelGGL(gemm_score, ggrid, dim3(256), 0, stream, F, E, S);
    hipLaunchKernelGGL(topk_loss, dim3(B_SZ), dim3(256), 0, stream,
                       S, targets, plabel, ptable, out);
}

// Round 2
// 250.353 us; speedup vs baseline: 1.1977x; 1.1977x over previous
//
#include <hip/hip_runtime.h>
#include <hip/hip_bf16.h>
#include <cstdint>

// Problem constants (match reference)
#define B_SZ     256
#define D_DIM    2048
#define N_PROXY  16384
#define P_POS    4
#define K_SEL    54        // BG_KNN + P
#define TEMP_INV 20.0f     // 1/0.05

typedef __bf16 bf16_t;
typedef __bf16 bf16x4 __attribute__((ext_vector_type(4)));
typedef __bf16 bf16x8 __attribute__((ext_vector_type(8)));
typedef float  f32x4  __attribute__((ext_vector_type(4)));

// ---------------------------------------------------------------------------
// Kernel 0: convert features fp32 -> bf16 once (1 MB, then L2-resident).
// 65536 threads x 8 floats.
// ---------------------------------------------------------------------------
__global__ __launch_bounds__(256)
void conv_feat(const float* __restrict__ F, bf16_t* __restrict__ Fb) {
    int i = blockIdx.x * 256 + threadIdx.x;          // 0..65535
    const float4* Fv = (const float4*)F;
    float4 a = Fv[2 * i], b = Fv[2 * i + 1];
    bf16x8 o = { (bf16_t)a.x, (bf16_t)a.y, (bf16_t)a.z, (bf16_t)a.w,
                 (bf16_t)b.x, (bf16_t)b.y, (bf16_t)b.z, (bf16_t)b.w };
    *(bf16x8*)(Fb + 8 * i) = o;
}

// ---------------------------------------------------------------------------
// Kernel 1: S = (F @ em.T)/TEMP.  BM=256 (all rows, em read ONCE), BN=64,
// BK=64. 256 threads = 4 waves, wave-tile 64x64 (wave = m-block).
// A-fragments straight from global bf16 (L2-hot, no LDS). B (em) fp32
// streamed with 2-deep register prefetch into double-buffered LDS.
// Grid = 256 blocks = 1/CU; latency hidden by in-flight loads, not TLP.
// ---------------------------------------------------------------------------
#define LDB 72   // bf16 per LDS row: 64 + 8 pad (144 B rows, 2-way alias only)

__global__ __launch_bounds__(256)
void gemm_score(const bf16_t* __restrict__ Fb, const float* __restrict__ E,
                float* __restrict__ S) {
    const int tid  = threadIdx.x;
    const int bn   = blockIdx.x;          // n-stripe: 64 em rows
    const int lane = tid & 63;
    const int wave = tid >> 6;            // m-block of 64 C rows
    const int frow = lane & 15;
    const int quad = lane >> 4;

    __shared__ bf16_t Bs[2][64 * LDB];

    f32x4 acc[4][4] = {};                 // [m][n]

    const float* Ebase = E + (size_t)(bn * 64) * D_DIM;

    // staging map: slot s = j*256+tid -> row = s>>4 (64 rows x 16 float4)
    int srow[4], scol[4];
    const float4* spv[4];
#pragma unroll
    for (int j = 0; j < 4; ++j) {
        int s = j * 256 + tid;
        srow[j] = s >> 4;
        scol[j] = s & 15;
        spv[j]  = (const float4*)(Ebase + (size_t)srow[j] * D_DIM) + scol[j];
    }
    const bf16_t* arow[4];
#pragma unroll
    for (int m = 0; m < 4; ++m)
        arow[m] = Fb + (size_t)(wave * 64 + m * 16 + frow) * D_DIM + quad * 8;

    float4 rg[2][4];       // B prefetch, 2 deep
    bf16x8 ar[2][4][2];    // A frags, 1 deep: [bank][m][ksub]

    // ---- prologue: kt=0 and kt=1 B loads; kt=0 A frags; prime LDS[0] ----
#pragma unroll
    for (int j = 0; j < 4; ++j) rg[0][j] = spv[j][0];
#pragma unroll
    for (int j = 0; j < 4; ++j) rg[1][j] = spv[j][16];
#pragma unroll
    for (int m = 0; m < 4; ++m)
#pragma unroll
        for (int ks = 0; ks < 2; ++ks)
            ar[0][m][ks] = *(const bf16x8*)(arow[m] + ks * 32);
#pragma unroll
    for (int j = 0; j < 4; ++j) {
        float4 v = rg[0][j];
        bf16x4 h = { (bf16_t)v.x, (bf16_t)v.y, (bf16_t)v.z, (bf16_t)v.w };
        *(bf16x4*)&Bs[0][srow[j] * LDB + scol[j] * 4] = h;
    }
    __syncthreads();

#define GEMM_STEP(KT, CUR)                                                      \
    {                                                                           \
        const int nxt_ = 1 - (CUR);                                             \
        if ((KT) + 2 < 32) {                                                    \
            _Pragma("unroll")                                                   \
            for (int j = 0; j < 4; ++j) rg[CUR][j] = spv[j][((KT) + 2) * 16];   \
        }                                                                       \
        if ((KT) + 1 < 32) {                                                    \
            _Pragma("unroll")                                                   \
            for (int m = 0; m < 4; ++m)                                         \
                _Pragma("unroll")                                               \
                for (int ks = 0; ks < 2; ++ks)                                  \
                    ar[nxt_][m][ks] =                                           \
                        *(const bf16x8*)(arow[m] + ((KT) + 1) * 64 + ks * 32);  \
        }                                                                       \
        _Pragma("unroll")                                                       \
        for (int ks = 0; ks < 2; ++ks) {                                        \
            bf16x8 bfrag[4];                                                    \
            _Pragma("unroll")                                                   \
            for (int n = 0; n < 4; ++n)                                         \
                bfrag[n] = *(const bf16x8*)&Bs[CUR][(n * 16 + frow) * LDB +     \
                                                    ks * 32 + quad * 8];        \
            _Pragma("unroll")                                                   \
            for (int m = 0; m < 4; ++m)                                         \
                _Pragma("unroll")                                               \
                for (int n = 0; n < 4; ++n)                                     \
                    acc[m][n] = __builtin_amdgcn_mfma_f32_16x16x32_bf16(        \
                        ar[CUR][m][ks], bfrag[n], acc[m][n], 0, 0, 0);          \
        }                                                                       \
        if ((KT) + 1 < 32) {                                                    \
            _Pragma("unroll")                                                   \
            for (int j = 0; j < 4; ++j) {                                       \
                float4 v = rg[nxt_][j];                                         \
                bf16x4 h = { (bf16_t)v.x, (bf16_t)v.y,                          \
                             (bf16_t)v.z, (bf16_t)v.w };                        \
                *(bf16x4*)&Bs[nxt_][srow[j] * LDB + scol[j] * 4] = h;           \
            }                                                                   \
        }                                                                       \
        __syncthreads();                                                        \
    }

    for (int ktt = 0; ktt < 32; ktt += 2) {
        GEMM_STEP(ktt, 0)
        GEMM_STEP(ktt + 1, 1)
    }
#undef GEMM_STEP

    // ---- epilogue: C/D layout col=lane&15, row=quad*4+i; fold 1/TEMP ----
#pragma unroll
    for (int m = 0; m < 4; ++m) {
        int gr = wave * 64 + m * 16 + quad * 4;
#pragma unroll
        for (int n = 0; n < 4; ++n) {
            int gc = bn * 64 + n * 16 + frow;
#pragma unroll
            for (int i = 0; i < 4; ++i)
                S[(size_t)(gr + i) * N_PROXY + gc] = acc[m][n][i] * TEMP_INV;
        }
    }
}

// ---------------------------------------------------------------------------
// Kernel 2: per-row top-K + log-softmax loss. 512 threads (8 waves) per row,
// 32 keys/thread in registers (no spill). One radix pass with early exit;
// top-(P-d) via compaction of <=54 candidates + wave-max iterations.
// ---------------------------------------------------------------------------
__device__ __forceinline__ float key_to_float(uint32_t k) {
    uint32_t bits = (k & 0x80000000u) ? (k ^ 0x80000000u) : ~k;
    return __uint_as_float(bits);
}

__device__ __forceinline__ int block_sum_i(int v, int tid, volatile int* rbuf) {
#pragma unroll
    for (int o = 32; o > 0; o >>= 1) v += __shfl_down(v, o, 64);
    __syncthreads();
    if ((tid & 63) == 0) rbuf[tid >> 6] = v;
    __syncthreads();
    int s = 0;
#pragma unroll
    for (int w = 0; w < 8; ++w) s += rbuf[w];
    return s;
}

__device__ __forceinline__ float block_sum_f(float v, int tid, volatile float* rbuf) {
#pragma unroll
    for (int o = 32; o > 0; o >>= 1) v += __shfl_down(v, o, 64);
    __syncthreads();
    if ((tid & 63) == 0) rbuf[tid >> 6] = v;
    __syncthreads();
    float s = 0.0f;
#pragma unroll
    for (int w = 0; w < 8; ++w) s += rbuf[w];
    return s;
}

__device__ __forceinline__ uint32_t block_max_u(uint32_t v, int tid,
                                                volatile uint32_t* rbuf) {
#pragma unroll
    for (int o = 32; o > 0; o >>= 1) {
        uint32_t w = __shfl_down(v, o, 64);
        v = (w > v) ? w : v;
    }
    __syncthreads();
    if ((tid & 63) == 0) rbuf[tid >> 6] = v;
    __syncthreads();
    uint32_t r = 0;
#pragma unroll
    for (int w = 0; w < 8; ++w) r = rbuf[w] > r ? rbuf[w] : r;
    return r;
}

__global__ __launch_bounds__(512)
void topk_loss(const float* __restrict__ S, const int* __restrict__ targets,
               const int* __restrict__ plabel, const int* __restrict__ ptable,
               float* __restrict__ out) {
    const int b    = blockIdx.x;
    const int tid  = threadIdx.x;
    const int lane = tid & 63;
    const int wave = tid >> 6;

    __shared__ int      sh_pos[4];
    __shared__ float    sh_pv[4];
    __shared__ int      sh_d;
    __shared__ int      rbuf_i[8];
    __shared__ float    rbuf_f[8];
    __shared__ uint32_t rbuf_u[8];
    __shared__ uint32_t cand_ls[64];
    __shared__ int      candcnt;
    __shared__ float    sh_numbg;

    const float* row = S + (size_t)b * N_PROXY;

    if (tid == 0) {
        int t  = targets[b];
        int py = plabel[t];
        int pos[4]; int d = 0;
        for (int j = 0; j < 4; ++j) {
            int p = ptable[py * 4 + j];
            bool dup = false;
            for (int i = 0; i < d; ++i) dup = dup || (pos[i] == p);
            if (!dup) pos[d++] = p;
        }
        sh_d = d;
        for (int j = 0; j < 4; ++j) sh_pos[j] = (j < d) ? pos[j] : -1;
        for (int j = 0; j < 4; ++j) sh_pv[j]  = (j < d) ? row[pos[j]] : 0.0f;
        candcnt = 0;
    }
    __syncthreads();

    const int d  = sh_d;
    const int p0 = sh_pos[0], p1 = sh_pos[1], p2 = sh_pos[2], p3 = sh_pos[3];
    float pv[4];
#pragma unroll
    for (int j = 0; j < 4; ++j) pv[j] = sh_pv[j];

    // ---- 32 logits/thread as sortable keys; positives excluded (key=0) ----
    uint32_t keys[32];
#pragma unroll
    for (int j = 0; j < 8; ++j) {
        int f4 = j * 512 + tid;
        float4 v = *(const float4*)(row + (size_t)f4 * 4);
        float vv[4] = { v.x, v.y, v.z, v.w };
#pragma unroll
        for (int q = 0; q < 4; ++q) {
            int idx = f4 * 4 + q;
            bool isp = (idx == p0) | (idx == p1) | (idx == p2) | (idx == p3);
            uint32_t bits = __float_as_uint(vv[q]);
            uint32_t key  = (bits & 0x80000000u) ? ~bits : (bits | 0x80000000u);
            keys[j * 4 + q] = isp ? 0u : key;
        }
    }

    const int need = K_SEL - d;              // backgrounds in the top-54 set

    // ---- radix select with early exit: T s.t. count(>=T)==need, or exact
    //      need-th key after all 32 bits (ties handled by value-fill) ----
    uint32_t T = 0;
    for (int bit = 31; bit >= 0; --bit) {
        uint32_t cnd = T | (1u << bit);
        int c = 0;
#pragma unroll
        for (int j = 0; j < 32; ++j) c += (keys[j] >= cnd) ? 1 : 0;
        int ct = block_sum_i(c, tid, rbuf_i);
        if (ct >= need) {
            T = cnd;
            if (ct == need) break;           // selected set is exactly top-need
        }
    }
    const float vT = key_to_float(T);

    // ---- stability max over backgrounds + positives ----
    uint32_t kmax = 0;
#pragma unroll
    for (int j = 0; j < 32; ++j) kmax = keys[j] > kmax ? keys[j] : kmax;
    kmax = block_max_u(kmax, tid, rbuf_u);
    float mx = key_to_float(kmax);
    for (int j = 0; j < 4; ++j) if (j < d && pv[j] > mx) mx = pv[j];

    // ---- lse over selected set: strict-greater + tie fill + positives ----
    int c1 = 0; float se = 0.0f;
#pragma unroll
    for (int j = 0; j < 32; ++j) {
        if (keys[j] > T) { c1 += 1; se += __expf(key_to_float(keys[j]) - mx); }
    }
    int   c1t = block_sum_i(c1, tid, rbuf_i);
    float set = block_sum_f(se, tid, rbuf_f);
    set += (float)(need - c1t) * __expf(vT - mx);
    for (int j = 0; j < 4; ++j) if (j < d) set += __expf(pv[j] - mx);
    const float lse = mx + logf(set);

    // ---- numerator: distinct positives + top (P-d) background values ----
    float num = 0.0f;
    for (int j = 0; j < 4; ++j) if (j < d) num += pv[j];
    if (d < P_POS) {
        // compact strict-greater candidates (<= 54) into LDS
#pragma unroll
        for (int j = 0; j < 32; ++j) {
            if (keys[j] > T) {
                int p = atomicAdd(&candcnt, 1);
                cand_ls[p] = keys[j];
            }
        }
        __syncthreads();
        if (wave == 0) {
            const int cc = candcnt;
            uint32_t v = (lane < cc) ? cand_ls[lane] : T;   // pad with vT (exact)
            float s = 0.0f;
            const int need2 = P_POS - d;                    // 1..3
            for (int it = 0; it < need2; ++it) {
                uint32_t m = v;
#pragma unroll
                for (int o = 32; o > 0; o >>= 1) {
                    uint32_t w = __shfl_xor(m, o, 64);
                    m = (w > m) ? w : m;
                }
                s += key_to_float(m);
                unsigned long long msk = __ballot(v == m);
                int first = __ffsll(msk) - 1;
                if (lane == first) v = 0u;
            }
            if (lane == 0) sh_numbg = s;
        }
        __syncthreads();
        num += sh_numbg;
    }

    const float loss_b = lse - num * (1.0f / P_POS);
    if (tid == 0) atomicAdd(out, loss_b * (1.0f / B_SZ));
}

// ---------------------------------------------------------------------------
extern "C" void kernel_launch(void* const* d_in, const int* in_sizes, int n_in,
                              void* d_out, int out_size, void* d_ws, size_t ws_size,
                              hipStream_t stream) {
    const float* F       = (const float*)d_in[0];   // features [256,2048]
    const float* E       = (const float*)d_in[1];   // global_memory [16384,2048]
    const int*   targets = (const int*)d_in[2];     // [256]
    const int*   plabel  = (const int*)d_in[3];     // [32768]
    const int*   ptable  = (const int*)d_in[4];     // [4096,4]

    bf16_t* Fb = (bf16_t*)d_ws;                                  // 1 MB
    float*  Sc = (float*)((char*)d_ws + (size_t)B_SZ * D_DIM * 2); // 16 MB
    float*  out = (float*)d_out;

    hipMemsetAsync(d_out, 0, sizeof(float), stream);

    hipLaunchKernelGGL(conv_feat, dim3(256), dim3(256), 0, stream, F, Fb);
    hipLaunchKernelGGL(gemm_score, dim3(N_PROXY / 64), dim3(256), 0, stream,
                       Fb, E, Sc);
    hipLaunchKernelGGL(topk_loss, dim3(B_SZ), dim3(512), 0, stream,
                       Sc, targets, plabel, ptable, out);
}